// Round 11
// baseline (567.392 us; speedup 1.0000x reference)
//
#include <hip/hip_runtime.h>

#define N_NODES 50000
#define M_PAD   50048    // 782 * 64, zero-padded rows for MFMA tile staging
#define N_EDGES 600000
#define ETOT    650000   // N_EDGES + N_NODES self loops
#define EPS     1e-5f
#define SCAN_BLOCKS 196  // ceil(50000/256)

typedef short bf16x8 __attribute__((ext_vector_type(8)));
typedef float f32x4  __attribute__((ext_vector_type(4)));

static __device__ __forceinline__ float leaky(float v) { return v >= 0.f ? v : 0.2f * v; }

// round-to-nearest-even float -> bf16 bits
static __device__ __forceinline__ ushort f2bf(float f) {
  unsigned u = __float_as_uint(f);
  return (ushort)((u + 0x7fff + ((u >> 16) & 1)) >> 16);
}
static __device__ __forceinline__ float bf2f(ushort u) {
  return __uint_as_float(((unsigned)u) << 16);
}

// ---------------------------------------------------------------------------
// bf16 MFMA GEMM: C[M,Nfull] = A[M_PAD,K]bf16 @ Bt[Nfull,K]bf16^T.
// 64x64 tile, BK=64, 4 waves each computing a 32x32 quadrant via 16x16x32 MFMA.
// LDS XOR-swizzle (byte ^= (row&7)<<4) keeps fragment ds_read_b128 2-way max.
// OUTBF: emit bf16. PERM (requires OUTBF && Nfull==256): head-interleaved
// output layout col -> (col&63)*4 + (col>>6), i.e. hp[row][c*4+h].
// ---------------------------------------------------------------------------
template <int K, bool OUTBF, bool PERM>
__global__ __launch_bounds__(256) void gemm_bf16(
    const ushort* __restrict__ A, const ushort* __restrict__ Bt,
    void* __restrict__ C, int M, int Nfull) {
  __shared__ char As[64 * 128];   // 64 rows x 64 bf16 (128B)
  __shared__ char Bs[64 * 128];
  const int tid = threadIdx.x;
  const int w = tid >> 6, lane = tid & 63;
  const int wr = w >> 1, wc = w & 1;
  const int m0 = blockIdx.x * 64, n0 = blockIdx.y * 64;

  f32x4 acc[2][2] = {};

  for (int k0 = 0; k0 < K; k0 += 64) {
    __syncthreads();
#pragma unroll
    for (int j = 0; j < 2; ++j) {
      int i = tid + j * 256;               // 0..511 chunk id (16B chunks)
      int row = i >> 3;
      int cb = (i & 7) * 16;               // byte within 128B row
      int dst = row * 128 + (cb ^ ((row & 7) << 4));
      uint4 va = *(const uint4*)((const char*)A + ((size_t)(m0 + row) * K + k0) * 2 + cb);
      *(uint4*)(As + dst) = va;
      uint4 vb = *(const uint4*)((const char*)Bt + ((size_t)(n0 + row) * K + k0) * 2 + cb);
      *(uint4*)(Bs + dst) = vb;
    }
    __syncthreads();
#pragma unroll
    for (int c = 0; c < 2; ++c) {
      bf16x8 af[2], bfr[2];
      int kb = (lane >> 4) * 16 + c * 64;
#pragma unroll
      for (int m = 0; m < 2; ++m) {
        int lr = wr * 32 + m * 16 + (lane & 15);
        af[m] = *(const bf16x8*)(As + lr * 128 + (kb ^ ((lr & 7) << 4)));
      }
#pragma unroll
      for (int n = 0; n < 2; ++n) {
        int lr = wc * 32 + n * 16 + (lane & 15);
        bfr[n] = *(const bf16x8*)(Bs + lr * 128 + (kb ^ ((lr & 7) << 4)));
      }
#pragma unroll
      for (int m = 0; m < 2; ++m)
#pragma unroll
        for (int n = 0; n < 2; ++n)
          acc[m][n] = __builtin_amdgcn_mfma_f32_16x16x32_bf16(af[m], bfr[n], acc[m][n], 0, 0, 0);
    }
  }
#pragma unroll
  for (int m = 0; m < 2; ++m)
#pragma unroll
    for (int n = 0; n < 2; ++n)
#pragma unroll
      for (int i = 0; i < 4; ++i) {
        int row = m0 + wr * 32 + m * 16 + (lane >> 4) * 4 + i;
        int col = n0 + wc * 32 + n * 16 + (lane & 15);
        if (row < M) {
          if (OUTBF) {
            int oc = PERM ? (((col & 63) << 2) | (col >> 6)) : col;
            ((ushort*)C)[(size_t)row * Nfull + oc] = f2bf(acc[m][n][i]);
          } else {
            ((float*)C)[(size_t)row * Nfull + col] = acc[m][n][i];
          }
        }
      }
}

// cast x (fp32 [N_NODES,128]) -> bf16 [M_PAD,128], pad rows zeroed.
__global__ __launch_bounds__(256) void cast_x_bf16(const float* __restrict__ x, ushort* __restrict__ o) {
  int i = blockIdx.x * 256 + threadIdx.x;          // chunk of 4
  if (i >= M_PAD * 32) return;
  int i4 = i * 4;
  int row = i4 >> 7;
  ushort4 r;
  if (row < N_NODES) {
    const float4 v = *(const float4*)(x + i4);
    r.x = f2bf(v.x); r.y = f2bf(v.y); r.z = f2bf(v.z); r.w = f2bf(v.w);
  } else {
    r.x = r.y = r.z = r.w = 0;
  }
  *(ushort4*)(o + i4) = r;
}

// transpose-cast weights: W[K,N] fp32 -> Wt[N,K] bf16
__global__ __launch_bounds__(256) void tcast_w(const float* __restrict__ W, ushort* __restrict__ Wt,
                                               int K, int N) {
  int i = blockIdx.x * 256 + threadIdx.x;
  if (i >= K * N) return;
  int k = i / N, n = i - k * N;
  Wt[n * K + k] = f2bf(W[i]);
}

// ---------------------------------------------------------------------------
// Attention scores, standard layout h[row][h*64+c] (wave/row; 16-lane grp = head)
// ---------------------------------------------------------------------------
__global__ __launch_bounds__(256) void attn_scores_bf(
    const ushort* __restrict__ h, const float* __restrict__ a_src,
    const float* __restrict__ a_dst, float* __restrict__ ssrc, float* __restrict__ sdst) {
  const int wave = threadIdx.x >> 6, lane = threadIdx.x & 63;
  const int row = blockIdx.x * 4 + wave;
  if (row >= N_NODES) return;
  const ushort4 hv = *(const ushort4*)(h + (size_t)row * 256 + lane * 4);
  float h0 = bf2f(hv.x), h1 = bf2f(hv.y), h2 = bf2f(hv.z), h3 = bf2f(hv.w);
  const float4 as = *(const float4*)(a_src + lane * 4);
  const float4 ad = *(const float4*)(a_dst + lane * 4);
  float ps = h0 * as.x + h1 * as.y + h2 * as.z + h3 * as.w;
  float pd = h0 * ad.x + h1 * ad.y + h2 * ad.z + h3 * ad.w;
#pragma unroll
  for (int off = 1; off < 16; off <<= 1) {
    ps += __shfl_xor(ps, off);
    pd += __shfl_xor(pd, off);
  }
  if ((lane & 15) == 0) {
    int hh = lane >> 4;
    ssrc[row * 4 + hh] = ps;
    sdst[row * 4 + hh] = pd;
  }
}

// Attention scores, permuted layout hp[row][c*4+h]. Lane c holds heads 0..3 at
// col c; 4 head-sums reduced across the full wave.
__global__ __launch_bounds__(256) void attn_scores_perm(
    const ushort* __restrict__ hp, const float* __restrict__ a_src,
    const float* __restrict__ a_dst, float* __restrict__ ssrc, float* __restrict__ sdst) {
  const int wave = threadIdx.x >> 6, lane = threadIdx.x & 63;
  const int row = blockIdx.x * 4 + wave;
  if (row >= N_NODES) return;
  const ushort4 hv = *(const ushort4*)(hp + (size_t)row * 256 + lane * 4);
  float h0 = bf2f(hv.x), h1 = bf2f(hv.y), h2 = bf2f(hv.z), h3 = bf2f(hv.w);
  float s0 = h0 * a_src[lane],       d0 = h0 * a_dst[lane];
  float s1 = h1 * a_src[64 + lane],  d1 = h1 * a_dst[64 + lane];
  float s2 = h2 * a_src[128 + lane], d2 = h2 * a_dst[128 + lane];
  float s3 = h3 * a_src[192 + lane], d3 = h3 * a_dst[192 + lane];
#pragma unroll
  for (int off = 1; off < 64; off <<= 1) {
    s0 += __shfl_xor(s0, off); d0 += __shfl_xor(d0, off);
    s1 += __shfl_xor(s1, off); d1 += __shfl_xor(d1, off);
    s2 += __shfl_xor(s2, off); d2 += __shfl_xor(d2, off);
    s3 += __shfl_xor(s3, off); d3 += __shfl_xor(d3, off);
  }
  if (lane == 0) {
    float4 sv = { s0, s1, s2, s3 };
    float4 dv = { d0, d1, d2, d3 };
    *(float4*)(ssrc + row * 4) = sv;
    *(float4*)(sdst + row * 4) = dv;
  }
}

// ---------------------------------------------------------------------------
// CSR build
// ---------------------------------------------------------------------------
static __device__ __forceinline__ void edge_sd(const int* ei, int e, int& src, int& dst) {
  if (e < N_EDGES) { src = ei[e]; dst = ei[N_EDGES + e]; }
  else             { src = dst = e - N_EDGES; }
}

__global__ __launch_bounds__(256) void deg_count_int(const int* __restrict__ ei, int* __restrict__ degi) {
  int e = blockIdx.x * 256 + threadIdx.x;
  if (e >= ETOT) return;
  int dst = (e < N_EDGES) ? ei[N_EDGES + e] : (e - N_EDGES);
  atomicAdd(&degi[dst], 1);
}

__global__ __launch_bounds__(256) void scan1(const int* __restrict__ degi,
                                             int* __restrict__ partial, int* __restrict__ bsum) {
  __shared__ int sm[256];
  int i = blockIdx.x * 256 + threadIdx.x;
  int v = (i < N_NODES) ? degi[i] : 0;
  sm[threadIdx.x] = v;
  __syncthreads();
#pragma unroll
  for (int off = 1; off < 256; off <<= 1) {
    int t = (threadIdx.x >= off) ? sm[threadIdx.x - off] : 0;
    __syncthreads();
    sm[threadIdx.x] += t;
    __syncthreads();
  }
  if (i < N_NODES) partial[i] = sm[threadIdx.x] - v;
  if (threadIdx.x == 255) bsum[blockIdx.x] = sm[255];
}

__global__ __launch_bounds__(256) void scan2(int* __restrict__ bsum) {
  __shared__ int sm[256];
  int v = (threadIdx.x < SCAN_BLOCKS) ? bsum[threadIdx.x] : 0;
  sm[threadIdx.x] = v;
  __syncthreads();
#pragma unroll
  for (int off = 1; off < 256; off <<= 1) {
    int t = (threadIdx.x >= off) ? sm[threadIdx.x - off] : 0;
    __syncthreads();
    sm[threadIdx.x] += t;
    __syncthreads();
  }
  if (threadIdx.x < SCAN_BLOCKS) bsum[threadIdx.x] = sm[threadIdx.x] - v;
}

__global__ __launch_bounds__(256) void scan3(int* __restrict__ rowstart, const int* __restrict__ bsum,
                                             int* __restrict__ cursor, const int* __restrict__ degi,
                                             float* __restrict__ dinv) {
  int i = blockIdx.x * 256 + threadIdx.x;
  if (i >= N_NODES) return;
  int r = rowstart[i] + bsum[blockIdx.x];
  rowstart[i] = r;
  cursor[i] = r;
  dinv[i] = rsqrtf(fmaxf((float)degi[i], 1.0f));
}

// scatter src AND dst per CSR slot (dst needed by edge-parallel p kernel)
__global__ __launch_bounds__(256) void scatter_k(const int* __restrict__ ei,
                                                 int* __restrict__ cursor, int* __restrict__ csr,
                                                 int* __restrict__ csrd) {
  int e = blockIdx.x * 256 + threadIdx.x;
  if (e >= ETOT) return;
  int src, dst; edge_sd(ei, e, src, dst);
  int pos = atomicAdd(&cursor[dst], 1);
  csr[pos] = src;
  csrd[pos] = dst;
}

// ---------------------------------------------------------------------------
// Edge-parallel attention probabilities: pcsr[j][h] = exp(leaky(ssrc+sdst)).
// Each exp computed exactly once (vs wave-redundant in the gather loops).
// ---------------------------------------------------------------------------
__global__ __launch_bounds__(256) void edge_p(
    const int* __restrict__ csr, const int* __restrict__ csrd,
    const float* __restrict__ ssrc, const float* __restrict__ sdst,
    float* __restrict__ pcsr) {
  int e = blockIdx.x * 256 + threadIdx.x;
  if (e >= ETOT) return;
  int src = csr[e], dst = csrd[e];
  const float4 ss = *(const float4*)(ssrc + src * 4);
  const float4 sd = *(const float4*)(sdst + dst * 4);
  float4 p;
  p.x = __expf(leaky(ss.x + sd.x));
  p.y = __expf(leaky(ss.y + sd.y));
  p.z = __expf(leaky(ss.z + sd.z));
  p.w = __expf(leaky(ss.w + sd.w));
  *(float4*)(pcsr + (size_t)e * 4) = p;
}

// ---------------------------------------------------------------------------
// GAT aggregations (gather over CSR, precomputed p, 2-unrolled).
// ---------------------------------------------------------------------------
__global__ __launch_bounds__(256) void gat_agg1_bf(
    const int* __restrict__ rowstart, const int* __restrict__ degi, const int* __restrict__ csr,
    const float* __restrict__ pcsr, const ushort* __restrict__ h, float* __restrict__ outp) {
  int dst = blockIdx.x * 4 + (threadIdx.x >> 6);
  if (dst >= N_NODES) return;
  int lane = threadIdx.x & 63;
  int hh = lane >> 4;
  int rs = rowstart[dst], re = rs + degi[dst];
  float z = 0.f;
  float ax = 0.f, ay = 0.f, az = 0.f, aw = 0.f;
  int j = rs;
  for (; j + 1 < re; j += 2) {
    int s0 = csr[j], s1 = csr[j + 1];
    float p0 = pcsr[(size_t)j * 4 + hh];
    float p1 = pcsr[(size_t)(j + 1) * 4 + hh];
    const ushort4 hv0 = *(const ushort4*)(h + (size_t)s0 * 256 + lane * 4);
    const ushort4 hv1 = *(const ushort4*)(h + (size_t)s1 * 256 + lane * 4);
    z += p0 + p1;
    ax += p0 * bf2f(hv0.x) + p1 * bf2f(hv1.x);
    ay += p0 * bf2f(hv0.y) + p1 * bf2f(hv1.y);
    az += p0 * bf2f(hv0.z) + p1 * bf2f(hv1.z);
    aw += p0 * bf2f(hv0.w) + p1 * bf2f(hv1.w);
  }
  if (j < re) {
    int s0 = csr[j];
    float p0 = pcsr[(size_t)j * 4 + hh];
    const ushort4 hv0 = *(const ushort4*)(h + (size_t)s0 * 256 + lane * 4);
    z += p0;
    ax += p0 * bf2f(hv0.x); ay += p0 * bf2f(hv0.y);
    az += p0 * bf2f(hv0.z); aw += p0 * bf2f(hv0.w);
  }
  float inv = 1.f / z;
  float4 o = { ax * inv, ay * inv, az * inv, aw * inv };
  *(float4*)(outp + (size_t)dst * 256 + lane * 4) = o;
}

// layer-2 aggregation over PERMUTED h2 (hp[row][c*4+h]); one ushort4/lane/edge
__global__ __launch_bounds__(256) void gat_agg2_perm(
    const int* __restrict__ rowstart, const int* __restrict__ degi, const int* __restrict__ csr,
    const float* __restrict__ pcsr, const ushort* __restrict__ hp, float* __restrict__ outp) {
  int dst = blockIdx.x * 4 + (threadIdx.x >> 6);
  if (dst >= N_NODES) return;
  int lane = threadIdx.x & 63;
  int rs = rowstart[dst], re = rs + degi[dst];
  float z0 = 0.f, z1 = 0.f, z2 = 0.f, z3 = 0.f;
  float a0 = 0.f, a1 = 0.f, a2 = 0.f, a3 = 0.f;
  int j = rs;
  for (; j + 1 < re; j += 2) {
    int s0 = csr[j], s1 = csr[j + 1];
    const float4 p0 = *(const float4*)(pcsr + (size_t)j * 4);
    const float4 p1 = *(const float4*)(pcsr + (size_t)(j + 1) * 4);
    const ushort4 hv0 = *(const ushort4*)(hp + (size_t)s0 * 256 + lane * 4);
    const ushort4 hv1 = *(const ushort4*)(hp + (size_t)s1 * 256 + lane * 4);
    z0 += p0.x + p1.x; z1 += p0.y + p1.y; z2 += p0.z + p1.z; z3 += p0.w + p1.w;
    a0 += p0.x * bf2f(hv0.x) + p1.x * bf2f(hv1.x);
    a1 += p0.y * bf2f(hv0.y) + p1.y * bf2f(hv1.y);
    a2 += p0.z * bf2f(hv0.z) + p1.z * bf2f(hv1.z);
    a3 += p0.w * bf2f(hv0.w) + p1.w * bf2f(hv1.w);
  }
  if (j < re) {
    int s0 = csr[j];
    const float4 p0 = *(const float4*)(pcsr + (size_t)j * 4);
    const ushort4 hv0 = *(const ushort4*)(hp + (size_t)s0 * 256 + lane * 4);
    z0 += p0.x; z1 += p0.y; z2 += p0.z; z3 += p0.w;
    a0 += p0.x * bf2f(hv0.x); a1 += p0.y * bf2f(hv0.y);
    a2 += p0.z * bf2f(hv0.z); a3 += p0.w * bf2f(hv0.w);
  }
  outp[(size_t)dst * 64 + lane] = 0.25f * (a0 / z0 + a1 / z1 + a2 / z2 + a3 / z3);
}

// GCN layer-1 aggregation + bias + ReLU; bf16 in (g1), bf16 out
__global__ __launch_bounds__(256) void gcn_agg_relu_bf(
    const int* __restrict__ rowstart, const int* __restrict__ degi, const int* __restrict__ csr,
    const ushort* __restrict__ g, const float* __restrict__ dinv, const float* __restrict__ bias,
    ushort* __restrict__ outp) {
  int dst = blockIdx.x * 4 + (threadIdx.x >> 6);
  if (dst >= N_NODES) return;
  int lane = threadIdx.x & 63;
  int rs = rowstart[dst], re = rs + degi[dst];
  float acc = 0.f;
  int j = rs;
  for (; j + 1 < re; j += 2) {
    int s0 = csr[j], s1 = csr[j + 1];
    float d0 = dinv[s0], d1 = dinv[s1];
    float v0 = bf2f(g[(size_t)s0 * 64 + lane]);
    float v1 = bf2f(g[(size_t)s1 * 64 + lane]);
    acc += d0 * v0 + d1 * v1;
  }
  if (j < re) {
    int s0 = csr[j];
    acc += dinv[s0] * bf2f(g[(size_t)s0 * 64 + lane]);
  }
  float v = acc * dinv[dst] + bias[lane];
  outp[(size_t)dst * 64 + lane] = f2bf(fmaxf(v, 0.f));
}

// GCN layer-2 aggregation (bf16 g2) + bias, fused with drift-weighted combine
__global__ __launch_bounds__(256) void gcn_agg_fuse_bf(
    const int* __restrict__ rowstart, const int* __restrict__ degi, const int* __restrict__ csr,
    const ushort* __restrict__ g2, const float* __restrict__ dinv, const float* __restrict__ bg2,
    const float* __restrict__ hgat, const float* __restrict__ b2, const float* __restrict__ dw,
    float* __restrict__ outp) {
  int dst = blockIdx.x * 4 + (threadIdx.x >> 6);
  if (dst >= N_NODES) return;
  int lane = threadIdx.x & 63;
  int rs = rowstart[dst], re = rs + degi[dst];
  float acc = 0.f;
  int j = rs;
  for (; j + 1 < re; j += 2) {
    int s0 = csr[j], s1 = csr[j + 1];
    float d0 = dinv[s0], d1 = dinv[s1];
    float v0 = bf2f(g2[(size_t)s0 * 64 + lane]);
    float v1 = bf2f(g2[(size_t)s1 * 64 + lane]);
    acc += d0 * v0 + d1 * v1;
  }
  if (j < re) {
    int s0 = csr[j];
    acc += dinv[s0] * bf2f(g2[(size_t)s0 * 64 + lane]);
  }
  float w = dw[0];
  float gcn = acc * dinv[dst] + bg2[lane];
  float gat = hgat[(size_t)dst * 64 + lane] + b2[lane];
  outp[(size_t)dst * 64 + lane] = w * gat + (1.f - w) * gcn;
}

// ---------------------------------------------------------------------------
// BatchNorm
// ---------------------------------------------------------------------------
__global__ __launch_bounds__(256) void bn_stats(
    const float* __restrict__ x, float* __restrict__ sum, float* __restrict__ sumsq) {
  int f = threadIdx.x;
  int r0 = blockIdx.x * 64;
  int rend = min(r0 + 64, N_NODES);
  float s = 0.f, s2 = 0.f;
  for (int r = r0; r < rend; ++r) {
    float v = x[(size_t)r * 256 + f];
    s += v; s2 += v * v;
  }
  atomicAdd(&sum[f], s);
  atomicAdd(&sumsq[f], s2);
}

// BN + ELU, emits bf16 directly (A operand of the W2 MFMA GEMM)
__global__ __launch_bounds__(256) void bn_apply_bf16(
    const float* __restrict__ x, const float* __restrict__ sum, const float* __restrict__ sumsq,
    const float* __restrict__ gamma, const float* __restrict__ beta, ushort* __restrict__ o) {
  size_t i = (size_t)blockIdx.x * 256 + threadIdx.x;
  if (i >= (size_t)N_NODES * 256) return;
  int f = (int)(i & 255);
  const float invN = 1.0f / N_NODES;
  float mu = sum[f] * invN;
  float var = sumsq[f] * invN - mu * mu;
  float v = (x[i] - mu) * rsqrtf(var + EPS) * gamma[f] + beta[f];
  float e = v > 0.f ? v : expf(v) - 1.0f;
  o[i] = f2bf(e);
}

extern "C" void kernel_launch(void* const* d_in, const int* in_sizes, int n_in,
                              void* d_out, int out_size, void* d_ws, size_t ws_size,
                              hipStream_t stream) {
  const float* x     = (const float*)d_in[0];
  const int*   ei    = (const int*)d_in[1];
  const float* dw    = (const float*)d_in[2];
  const float* W1    = (const float*)d_in[3];
  const float* as1   = (const float*)d_in[4];
  const float* ad1   = (const float*)d_in[5];
  // d_in[6] = b1: cancels through BatchNorm
  const float* gamma = (const float*)d_in[7];
  const float* beta  = (const float*)d_in[8];
  const float* W2    = (const float*)d_in[9];
  const float* as2   = (const float*)d_in[10];
  const float* ad2   = (const float*)d_in[11];
  const float* b2    = (const float*)d_in[12];
  const float* Wg1   = (const float*)d_in[13];
  const float* bg1   = (const float*)d_in[14];
  const float* Wg2   = (const float*)d_in[15];
  const float* bg2   = (const float*)d_in[16];
  float* out = (float*)d_out;

  char* p = (char*)d_ws;
  size_t off = 0;
  auto alloc = [&](size_t bytes) {
    char* r = p + off;
    off = (off + bytes + 255) & ~(size_t)255;
    return r;
  };
  float*  bufB  = (float*)alloc((size_t)N_NODES * 256 * 4);   // agg1 fp32; later overlaid by h2 perm bf16
  float*  bufC  = (float*)alloc((size_t)N_NODES * 64 * 4);    // h_gat fp32
  ushort* xbf   = (ushort*)alloc((size_t)M_PAD * 128 * 2);    // x bf16 (GEMM-A, padded)
  ushort* R1    = (ushort*)alloc((size_t)M_PAD * 256 * 2);    // h1bf, then hbn bf16 (GEMM-A, padded)
  ushort* g1bf  = (ushort*)alloc((size_t)N_NODES * 64 * 2);
  ushort* gbf   = (ushort*)alloc((size_t)M_PAD * 64 * 2);     // relu(g) bf16 (GEMM-A, padded)
  ushort* g2bf  = (ushort*)alloc((size_t)N_NODES * 64 * 2);
  ushort* w1t   = (ushort*)alloc((size_t)256 * 128 * 2);
  ushort* w2t   = (ushort*)alloc((size_t)256 * 256 * 2);
  ushort* wg1t  = (ushort*)alloc((size_t)64 * 128 * 2);
  ushort* wg2t  = (ushort*)alloc((size_t)64 * 64 * 2);
  float*  ssrc1 = (float*)alloc((size_t)N_NODES * 4 * 4);
  float*  sdst1 = (float*)alloc((size_t)N_NODES * 4 * 4);
  float*  ssrc2 = (float*)alloc((size_t)N_NODES * 4 * 4);
  float*  sdst2 = (float*)alloc((size_t)N_NODES * 4 * 4);
  int*    degi  = (int*)alloc((size_t)N_NODES * 4);
  int*    rowst = (int*)alloc((size_t)N_NODES * 4);
  int*    cursor= (int*)alloc((size_t)N_NODES * 4);
  int*    bsum  = (int*)alloc(SCAN_BLOCKS * 4);
  float*  dinv  = (float*)alloc((size_t)N_NODES * 4);
  int*    csr   = (int*)alloc((size_t)ETOT * 4);
  int*    csrd  = (int*)alloc((size_t)ETOT * 4);
  float*  pcsr  = (float*)alloc((size_t)ETOT * 4 * 4);        // per-edge probs [ETOT][4]
  float*  bnsum = (float*)alloc(256 * 4);
  float*  bnsq  = (float*)alloc(256 * 4);
  ushort* h2p   = (ushort*)bufB;   // overlay: bufB fp32 dead after bn_apply; holds permuted h2

  const dim3 blk(256);
  const int egrid = (ETOT + 255) / 256;
  const int ngrid = 12500;

  hipMemsetAsync(degi, 0, (size_t)N_NODES * 4, stream);
  hipMemsetAsync(bnsum, 0, 256 * 4, stream);
  hipMemsetAsync(bnsq, 0, 256 * 4, stream);
  // zero GEMM-A pad rows (row-guarded writes never touch them afterwards)
  hipMemsetAsync(R1 + (size_t)N_NODES * 256, 0, (size_t)(M_PAD - N_NODES) * 256 * 2, stream);
  hipMemsetAsync(gbf + (size_t)N_NODES * 64, 0, (size_t)(M_PAD - N_NODES) * 64 * 2, stream);

  // ---- CSR build + bf16 prep ----
  deg_count_int<<<egrid, blk, 0, stream>>>(ei, degi);
  scan1<<<SCAN_BLOCKS, blk, 0, stream>>>(degi, rowst, bsum);
  scan2<<<1, blk, 0, stream>>>(bsum);
  scan3<<<SCAN_BLOCKS, blk, 0, stream>>>(rowst, bsum, cursor, degi, dinv);
  scatter_k<<<egrid, blk, 0, stream>>>(ei, cursor, csr, csrd);
  cast_x_bf16<<<(M_PAD * 32 + 255) / 256, blk, 0, stream>>>(x, xbf);
  tcast_w<<<(128 * 256 + 255) / 256, blk, 0, stream>>>(W1, w1t, 128, 256);
  tcast_w<<<(256 * 256 + 255) / 256, blk, 0, stream>>>(W2, w2t, 256, 256);
  tcast_w<<<(128 * 64 + 255) / 256, blk, 0, stream>>>(Wg1, wg1t, 128, 64);
  tcast_w<<<(64 * 64 + 255) / 256, blk, 0, stream>>>(Wg2, wg2t, 64, 64);

  // ---- GEMMs off x (xbf dead after these) ----
  gemm_bf16<128, true, false><<<dim3(782, 4), blk, 0, stream>>>(xbf, w1t, R1, N_NODES, 256);    // h1
  gemm_bf16<128, true, false><<<dim3(782, 1), blk, 0, stream>>>(xbf, wg1t, g1bf, N_NODES, 64);  // g1

  // ---- GAT layer 1 ----
  attn_scores_bf<<<ngrid, blk, 0, stream>>>(R1, as1, ad1, ssrc1, sdst1);
  edge_p<<<egrid, blk, 0, stream>>>(csr, csrd, ssrc1, sdst1, pcsr);
  gat_agg1_bf<<<ngrid, blk, 0, stream>>>(rowst, degi, csr, pcsr, R1, bufB);

  // ---- GCN layer 1 (independent) ----
  gcn_agg_relu_bf<<<ngrid, blk, 0, stream>>>(rowst, degi, csr, g1bf, dinv, bg1, gbf);
  gemm_bf16<64, true, false><<<dim3(782, 1), blk, 0, stream>>>(gbf, wg2t, g2bf, N_NODES, 64);   // g2

  // ---- BatchNorm + ELU -> hbn bf16 (reuses R1; h1bf dead) ----
  bn_stats<<<(N_NODES + 63) / 64, blk, 0, stream>>>(bufB, bnsum, bnsq);
  bn_apply_bf16<<<(int)(((size_t)N_NODES * 256 + 255) / 256), blk, 0, stream>>>(
      bufB, bnsum, bnsq, gamma, beta, R1);

  // ---- GAT layer 2: h2 written head-interleaved (h2p overlays dead bufB) ----
  gemm_bf16<256, true, true><<<dim3(782, 4), blk, 0, stream>>>(R1, w2t, h2p, N_NODES, 256);     // h2 perm
  attn_scores_perm<<<ngrid, blk, 0, stream>>>(h2p, as2, ad2, ssrc2, sdst2);
  edge_p<<<egrid, blk, 0, stream>>>(csr, csrd, ssrc2, sdst2, pcsr);
  gat_agg2_perm<<<ngrid, blk, 0, stream>>>(rowst, degi, csr, pcsr, h2p, bufC);

  // ---- GCN layer 2 + drift-weighted fusion ----
  gcn_agg_fuse_bf<<<ngrid, blk, 0, stream>>>(rowst, degi, csr, g2bf, dinv, bg2, bufC, b2, dw, out);
}

// Round 12
// 495.281 us; speedup vs baseline: 1.1456x; 1.1456x over previous
//
#include <hip/hip_runtime.h>

#define N_NODES 50000
#define M_PAD   50048    // 782 * 64, zero-padded rows for MFMA tile staging
#define N_EDGES 600000
#define ETOT    650000   // N_EDGES + N_NODES self loops
#define EPS     1e-5f
#define SCAN_BLOCKS 196  // ceil(50000/256)

typedef short bf16x8 __attribute__((ext_vector_type(8)));
typedef float f32x4  __attribute__((ext_vector_type(4)));

static __device__ __forceinline__ float leaky(float v) { return v >= 0.f ? v : 0.2f * v; }

// round-to-nearest-even float -> bf16 bits
static __device__ __forceinline__ ushort f2bf(float f) {
  unsigned u = __float_as_uint(f);
  return (ushort)((u + 0x7fff + ((u >> 16) & 1)) >> 16);
}
static __device__ __forceinline__ float bf2f(ushort u) {
  return __uint_as_float(((unsigned)u) << 16);
}

// ---------------------------------------------------------------------------
// bf16 MFMA GEMM: C[M,Nfull] = A[M_PAD,K]bf16 @ Bt[Nfull,K]bf16^T.
// 64x64 tile, BK=64, 4 waves each computing a 32x32 quadrant via 16x16x32 MFMA.
// LDS XOR-swizzle (byte ^= (row&7)<<4) keeps fragment ds_read_b128 2-way max.
// OUTBF: emit bf16. PERM (requires OUTBF && Nfull==256): head-interleaved
// output layout col -> (col&63)*4 + (col>>6), i.e. hp[row][c*4+h].
// ---------------------------------------------------------------------------
template <int K, bool OUTBF, bool PERM>
__global__ __launch_bounds__(256) void gemm_bf16(
    const ushort* __restrict__ A, const ushort* __restrict__ Bt,
    void* __restrict__ C, int M, int Nfull) {
  __shared__ char As[64 * 128];   // 64 rows x 64 bf16 (128B)
  __shared__ char Bs[64 * 128];
  const int tid = threadIdx.x;
  const int w = tid >> 6, lane = tid & 63;
  const int wr = w >> 1, wc = w & 1;
  const int m0 = blockIdx.x * 64, n0 = blockIdx.y * 64;

  f32x4 acc[2][2] = {};

  for (int k0 = 0; k0 < K; k0 += 64) {
    __syncthreads();
#pragma unroll
    for (int j = 0; j < 2; ++j) {
      int i = tid + j * 256;               // 0..511 chunk id (16B chunks)
      int row = i >> 3;
      int cb = (i & 7) * 16;               // byte within 128B row
      int dst = row * 128 + (cb ^ ((row & 7) << 4));
      uint4 va = *(const uint4*)((const char*)A + ((size_t)(m0 + row) * K + k0) * 2 + cb);
      *(uint4*)(As + dst) = va;
      uint4 vb = *(const uint4*)((const char*)Bt + ((size_t)(n0 + row) * K + k0) * 2 + cb);
      *(uint4*)(Bs + dst) = vb;
    }
    __syncthreads();
#pragma unroll
    for (int c = 0; c < 2; ++c) {
      bf16x8 af[2], bfr[2];
      int kb = (lane >> 4) * 16 + c * 64;
#pragma unroll
      for (int m = 0; m < 2; ++m) {
        int lr = wr * 32 + m * 16 + (lane & 15);
        af[m] = *(const bf16x8*)(As + lr * 128 + (kb ^ ((lr & 7) << 4)));
      }
#pragma unroll
      for (int n = 0; n < 2; ++n) {
        int lr = wc * 32 + n * 16 + (lane & 15);
        bfr[n] = *(const bf16x8*)(Bs + lr * 128 + (kb ^ ((lr & 7) << 4)));
      }
#pragma unroll
      for (int m = 0; m < 2; ++m)
#pragma unroll
        for (int n = 0; n < 2; ++n)
          acc[m][n] = __builtin_amdgcn_mfma_f32_16x16x32_bf16(af[m], bfr[n], acc[m][n], 0, 0, 0);
    }
  }
#pragma unroll
  for (int m = 0; m < 2; ++m)
#pragma unroll
    for (int n = 0; n < 2; ++n)
#pragma unroll
      for (int i = 0; i < 4; ++i) {
        int row = m0 + wr * 32 + m * 16 + (lane >> 4) * 4 + i;
        int col = n0 + wc * 32 + n * 16 + (lane & 15);
        if (row < M) {
          if (OUTBF) {
            int oc = PERM ? (((col & 63) << 2) | (col >> 6)) : col;
            ((ushort*)C)[(size_t)row * Nfull + oc] = f2bf(acc[m][n][i]);
          } else {
            ((float*)C)[(size_t)row * Nfull + col] = acc[m][n][i];
          }
        }
      }
}

// cast x (fp32 [N_NODES,128]) -> bf16 [M_PAD,128], pad rows zeroed.
__global__ __launch_bounds__(256) void cast_x_bf16(const float* __restrict__ x, ushort* __restrict__ o) {
  int i = blockIdx.x * 256 + threadIdx.x;          // chunk of 4
  if (i >= M_PAD * 32) return;
  int i4 = i * 4;
  int row = i4 >> 7;
  ushort4 r;
  if (row < N_NODES) {
    const float4 v = *(const float4*)(x + i4);
    r.x = f2bf(v.x); r.y = f2bf(v.y); r.z = f2bf(v.z); r.w = f2bf(v.w);
  } else {
    r.x = r.y = r.z = r.w = 0;
  }
  *(ushort4*)(o + i4) = r;
}

// ---------------------------------------------------------------------------
// Fused small-prep: pad-row zeroing (R1, aggbf, gbf) + 4 weight transpose-casts.
// Segments by blockIdx.x; 459 blocks total.
// ---------------------------------------------------------------------------
__global__ __launch_bounds__(256) void prep_small(
    const float* __restrict__ W1, const float* __restrict__ W2,
    const float* __restrict__ Wg1, const float* __restrict__ Wg2,
    ushort* __restrict__ w1t, ushort* __restrict__ w2t,
    ushort* __restrict__ wg1t, ushort* __restrict__ wg2t,
    ushort* __restrict__ r1pad, ushort* __restrict__ aggpad, ushort* __restrict__ gpad) {
  int bid = blockIdx.x, t = threadIdx.x;
  ushort4 zz; zz.x = zz.y = zz.z = zz.w = 0;
  if (bid < 12) {                                   // R1 pad: 3072 ushort4
    int i = bid * 256 + t;
    *(ushort4*)(r1pad + i * 4) = zz;
  } else if (bid < 24) {                            // aggbf pad: 3072 ushort4
    int i = (bid - 12) * 256 + t;
    *(ushort4*)(aggpad + i * 4) = zz;
  } else if (bid < 27) {                            // gbf pad: 768 ushort4
    int i = (bid - 24) * 256 + t;
    if (i < 768) *(ushort4*)(gpad + i * 4) = zz;
  } else if (bid < 155) {                           // w1t: [128,256] -> [256,128]
    int i = (bid - 27) * 256 + t;
    int k = i >> 8, n = i & 255;
    w1t[n * 128 + k] = f2bf(W1[i]);
  } else if (bid < 411) {                           // w2t: [256,256] -> [256,256]
    int i = (bid - 155) * 256 + t;
    int k = i >> 8, n = i & 255;
    w2t[n * 256 + k] = f2bf(W2[i]);
  } else if (bid < 443) {                           // wg1t: [128,64] -> [64,128]
    int i = (bid - 411) * 256 + t;
    int k = i >> 6, n = i & 63;
    wg1t[n * 128 + k] = f2bf(Wg1[i]);
  } else {                                          // wg2t: [64,64] -> [64,64]
    int i = (bid - 443) * 256 + t;
    int k = i >> 6, n = i & 63;
    wg2t[n * 64 + k] = f2bf(Wg2[i]);
  }
}

// ---------------------------------------------------------------------------
// Attention scores, standard layout h[row][h*64+c] (wave/row; 16-lane grp = head)
// ---------------------------------------------------------------------------
__global__ __launch_bounds__(256) void attn_scores_bf(
    const ushort* __restrict__ h, const float* __restrict__ a_src,
    const float* __restrict__ a_dst, float* __restrict__ ssrc, float* __restrict__ sdst) {
  const int wave = threadIdx.x >> 6, lane = threadIdx.x & 63;
  const int row = blockIdx.x * 4 + wave;
  if (row >= N_NODES) return;
  const ushort4 hv = *(const ushort4*)(h + (size_t)row * 256 + lane * 4);
  float h0 = bf2f(hv.x), h1 = bf2f(hv.y), h2 = bf2f(hv.z), h3 = bf2f(hv.w);
  const float4 as = *(const float4*)(a_src + lane * 4);
  const float4 ad = *(const float4*)(a_dst + lane * 4);
  float ps = h0 * as.x + h1 * as.y + h2 * as.z + h3 * as.w;
  float pd = h0 * ad.x + h1 * ad.y + h2 * ad.z + h3 * ad.w;
#pragma unroll
  for (int off = 1; off < 16; off <<= 1) {
    ps += __shfl_xor(ps, off);
    pd += __shfl_xor(pd, off);
  }
  if ((lane & 15) == 0) {
    int hh = lane >> 4;
    ssrc[row * 4 + hh] = ps;
    sdst[row * 4 + hh] = pd;
  }
}

// Attention scores, permuted layout hp[row][c*4+h].
__global__ __launch_bounds__(256) void attn_scores_perm(
    const ushort* __restrict__ hp, const float* __restrict__ a_src,
    const float* __restrict__ a_dst, float* __restrict__ ssrc, float* __restrict__ sdst) {
  const int wave = threadIdx.x >> 6, lane = threadIdx.x & 63;
  const int row = blockIdx.x * 4 + wave;
  if (row >= N_NODES) return;
  const ushort4 hv = *(const ushort4*)(hp + (size_t)row * 256 + lane * 4);
  float h0 = bf2f(hv.x), h1 = bf2f(hv.y), h2 = bf2f(hv.z), h3 = bf2f(hv.w);
  float s0 = h0 * a_src[lane],       d0 = h0 * a_dst[lane];
  float s1 = h1 * a_src[64 + lane],  d1 = h1 * a_dst[64 + lane];
  float s2 = h2 * a_src[128 + lane], d2 = h2 * a_dst[128 + lane];
  float s3 = h3 * a_src[192 + lane], d3 = h3 * a_dst[192 + lane];
#pragma unroll
  for (int off = 1; off < 64; off <<= 1) {
    s0 += __shfl_xor(s0, off); d0 += __shfl_xor(d0, off);
    s1 += __shfl_xor(s1, off); d1 += __shfl_xor(d1, off);
    s2 += __shfl_xor(s2, off); d2 += __shfl_xor(d2, off);
    s3 += __shfl_xor(s3, off); d3 += __shfl_xor(d3, off);
  }
  if (lane == 0) {
    float4 sv = { s0, s1, s2, s3 };
    float4 dv = { d0, d1, d2, d3 };
    *(float4*)(ssrc + row * 4) = sv;
    *(float4*)(sdst + row * 4) = dv;
  }
}

// ---------------------------------------------------------------------------
// CSR build
// ---------------------------------------------------------------------------
static __device__ __forceinline__ void edge_sd(const int* ei, int e, int& src, int& dst) {
  if (e < N_EDGES) { src = ei[e]; dst = ei[N_EDGES + e]; }
  else             { src = dst = e - N_EDGES; }
}

__global__ __launch_bounds__(256) void deg_count_int(const int* __restrict__ ei, int* __restrict__ degi) {
  int e = blockIdx.x * 256 + threadIdx.x;
  if (e >= ETOT) return;
  int dst = (e < N_EDGES) ? ei[N_EDGES + e] : (e - N_EDGES);
  atomicAdd(&degi[dst], 1);
}

__global__ __launch_bounds__(256) void scan1(const int* __restrict__ degi,
                                             int* __restrict__ partial, int* __restrict__ bsum) {
  __shared__ int sm[256];
  int i = blockIdx.x * 256 + threadIdx.x;
  int v = (i < N_NODES) ? degi[i] : 0;
  sm[threadIdx.x] = v;
  __syncthreads();
#pragma unroll
  for (int off = 1; off < 256; off <<= 1) {
    int t = (threadIdx.x >= off) ? sm[threadIdx.x - off] : 0;
    __syncthreads();
    sm[threadIdx.x] += t;
    __syncthreads();
  }
  if (i < N_NODES) partial[i] = sm[threadIdx.x] - v;
  if (threadIdx.x == 255) bsum[blockIdx.x] = sm[255];
}

__global__ __launch_bounds__(256) void scan2(int* __restrict__ bsum) {
  __shared__ int sm[256];
  int v = (threadIdx.x < SCAN_BLOCKS) ? bsum[threadIdx.x] : 0;
  sm[threadIdx.x] = v;
  __syncthreads();
#pragma unroll
  for (int off = 1; off < 256; off <<= 1) {
    int t = (threadIdx.x >= off) ? sm[threadIdx.x - off] : 0;
    __syncthreads();
    sm[threadIdx.x] += t;
    __syncthreads();
  }
  if (threadIdx.x < SCAN_BLOCKS) bsum[threadIdx.x] = sm[threadIdx.x] - v;
}

__global__ __launch_bounds__(256) void scan3(int* __restrict__ rowstart, const int* __restrict__ bsum,
                                             int* __restrict__ cursor, const int* __restrict__ degi,
                                             float* __restrict__ dinv) {
  int i = blockIdx.x * 256 + threadIdx.x;
  if (i >= N_NODES) return;
  int r = rowstart[i] + bsum[blockIdx.x];
  rowstart[i] = r;
  cursor[i] = r;
  dinv[i] = rsqrtf(fmaxf((float)degi[i], 1.0f));
}

// scatter src AND dst per CSR slot (dst needed by edge-parallel p kernel)
__global__ __launch_bounds__(256) void scatter_k(const int* __restrict__ ei,
                                                 int* __restrict__ cursor, int* __restrict__ csr,
                                                 int* __restrict__ csrd) {
  int e = blockIdx.x * 256 + threadIdx.x;
  if (e >= ETOT) return;
  int src, dst; edge_sd(ei, e, src, dst);
  int pos = atomicAdd(&cursor[dst], 1);
  csr[pos] = src;
  csrd[pos] = dst;
}

// ---------------------------------------------------------------------------
// Edge-parallel attention probabilities: pcsr[j][h] = exp(leaky(ssrc+sdst)).
// ---------------------------------------------------------------------------
__global__ __launch_bounds__(256) void edge_p(
    const int* __restrict__ csr, const int* __restrict__ csrd,
    const float* __restrict__ ssrc, const float* __restrict__ sdst,
    float* __restrict__ pcsr) {
  int e = blockIdx.x * 256 + threadIdx.x;
  if (e >= ETOT) return;
  int src = csr[e], dst = csrd[e];
  const float4 ss = *(const float4*)(ssrc + src * 4);
  const float4 sd = *(const float4*)(sdst + dst * 4);
  float4 p;
  p.x = __expf(leaky(ss.x + sd.x));
  p.y = __expf(leaky(ss.y + sd.y));
  p.z = __expf(leaky(ss.z + sd.z));
  p.w = __expf(leaky(ss.w + sd.w));
  *(float4*)(pcsr + (size_t)e * 4) = p;
}

// ---------------------------------------------------------------------------
// GAT aggregations (gather over CSR, precomputed p, 4-unrolled).
// agg1 emits bf16 (BN pipeline runs on bf16).
// ---------------------------------------------------------------------------
__global__ __launch_bounds__(256) void gat_agg1_bf(
    const int* __restrict__ rowstart, const int* __restrict__ degi, const int* __restrict__ csr,
    const float* __restrict__ pcsr, const ushort* __restrict__ h, ushort* __restrict__ outp) {
  int dst = blockIdx.x * 4 + (threadIdx.x >> 6);
  if (dst >= N_NODES) return;
  int lane = threadIdx.x & 63;
  int hh = lane >> 4;
  int rs = rowstart[dst], re = rs + degi[dst];
  float z = 0.f;
  float ax = 0.f, ay = 0.f, az = 0.f, aw = 0.f;
  int j = rs;
  for (; j + 3 < re; j += 4) {
    int s0 = csr[j], s1 = csr[j + 1], s2 = csr[j + 2], s3 = csr[j + 3];
    float p0 = pcsr[(size_t)j * 4 + hh];
    float p1 = pcsr[(size_t)(j + 1) * 4 + hh];
    float p2 = pcsr[(size_t)(j + 2) * 4 + hh];
    float p3 = pcsr[(size_t)(j + 3) * 4 + hh];
    const ushort4 v0 = *(const ushort4*)(h + (size_t)s0 * 256 + lane * 4);
    const ushort4 v1 = *(const ushort4*)(h + (size_t)s1 * 256 + lane * 4);
    const ushort4 v2 = *(const ushort4*)(h + (size_t)s2 * 256 + lane * 4);
    const ushort4 v3 = *(const ushort4*)(h + (size_t)s3 * 256 + lane * 4);
    z += (p0 + p1) + (p2 + p3);
    ax += p0 * bf2f(v0.x) + p1 * bf2f(v1.x) + p2 * bf2f(v2.x) + p3 * bf2f(v3.x);
    ay += p0 * bf2f(v0.y) + p1 * bf2f(v1.y) + p2 * bf2f(v2.y) + p3 * bf2f(v3.y);
    az += p0 * bf2f(v0.z) + p1 * bf2f(v1.z) + p2 * bf2f(v2.z) + p3 * bf2f(v3.z);
    aw += p0 * bf2f(v0.w) + p1 * bf2f(v1.w) + p2 * bf2f(v2.w) + p3 * bf2f(v3.w);
  }
  for (; j < re; ++j) {
    int s0 = csr[j];
    float p0 = pcsr[(size_t)j * 4 + hh];
    const ushort4 v0 = *(const ushort4*)(h + (size_t)s0 * 256 + lane * 4);
    z += p0;
    ax += p0 * bf2f(v0.x); ay += p0 * bf2f(v0.y);
    az += p0 * bf2f(v0.z); aw += p0 * bf2f(v0.w);
  }
  float inv = 1.f / z;
  ushort4 o;
  o.x = f2bf(ax * inv); o.y = f2bf(ay * inv);
  o.z = f2bf(az * inv); o.w = f2bf(aw * inv);
  *(ushort4*)(outp + (size_t)dst * 256 + lane * 4) = o;
}

// layer-2 aggregation over PERMUTED h2 (hp[row][c*4+h]); one ushort4/lane/edge
__global__ __launch_bounds__(256) void gat_agg2_perm(
    const int* __restrict__ rowstart, const int* __restrict__ degi, const int* __restrict__ csr,
    const float* __restrict__ pcsr, const ushort* __restrict__ hp, float* __restrict__ outp) {
  int dst = blockIdx.x * 4 + (threadIdx.x >> 6);
  if (dst >= N_NODES) return;
  int lane = threadIdx.x & 63;
  int rs = rowstart[dst], re = rs + degi[dst];
  float z0 = 0.f, z1 = 0.f, z2 = 0.f, z3 = 0.f;
  float a0 = 0.f, a1 = 0.f, a2 = 0.f, a3 = 0.f;
  int j = rs;
  for (; j + 3 < re; j += 4) {
    int s0 = csr[j], s1 = csr[j + 1], s2 = csr[j + 2], s3 = csr[j + 3];
    const float4 p0 = *(const float4*)(pcsr + (size_t)j * 4);
    const float4 p1 = *(const float4*)(pcsr + (size_t)(j + 1) * 4);
    const float4 p2 = *(const float4*)(pcsr + (size_t)(j + 2) * 4);
    const float4 p3 = *(const float4*)(pcsr + (size_t)(j + 3) * 4);
    const ushort4 v0 = *(const ushort4*)(hp + (size_t)s0 * 256 + lane * 4);
    const ushort4 v1 = *(const ushort4*)(hp + (size_t)s1 * 256 + lane * 4);
    const ushort4 v2 = *(const ushort4*)(hp + (size_t)s2 * 256 + lane * 4);
    const ushort4 v3 = *(const ushort4*)(hp + (size_t)s3 * 256 + lane * 4);
    z0 += (p0.x + p1.x) + (p2.x + p3.x);
    z1 += (p0.y + p1.y) + (p2.y + p3.y);
    z2 += (p0.z + p1.z) + (p2.z + p3.z);
    z3 += (p0.w + p1.w) + (p2.w + p3.w);
    a0 += p0.x * bf2f(v0.x) + p1.x * bf2f(v1.x) + p2.x * bf2f(v2.x) + p3.x * bf2f(v3.x);
    a1 += p0.y * bf2f(v0.y) + p1.y * bf2f(v1.y) + p2.y * bf2f(v2.y) + p3.y * bf2f(v3.y);
    a2 += p0.z * bf2f(v0.z) + p1.z * bf2f(v1.z) + p2.z * bf2f(v2.z) + p3.z * bf2f(v3.z);
    a3 += p0.w * bf2f(v0.w) + p1.w * bf2f(v1.w) + p2.w * bf2f(v2.w) + p3.w * bf2f(v3.w);
  }
  for (; j < re; ++j) {
    int s0 = csr[j];
    const float4 p0 = *(const float4*)(pcsr + (size_t)j * 4);
    const ushort4 v0 = *(const ushort4*)(hp + (size_t)s0 * 256 + lane * 4);
    z0 += p0.x; z1 += p0.y; z2 += p0.z; z3 += p0.w;
    a0 += p0.x * bf2f(v0.x); a1 += p0.y * bf2f(v0.y);
    a2 += p0.z * bf2f(v0.z); a3 += p0.w * bf2f(v0.w);
  }
  outp[(size_t)dst * 64 + lane] = 0.25f * (a0 / z0 + a1 / z1 + a2 / z2 + a3 / z3);
}

// GCN layer-1 aggregation + bias + ReLU; bf16 in (g1), bf16 out
__global__ __launch_bounds__(256) void gcn_agg_relu_bf(
    const int* __restrict__ rowstart, const int* __restrict__ degi, const int* __restrict__ csr,
    const ushort* __restrict__ g, const float* __restrict__ dinv, const float* __restrict__ bias,
    ushort* __restrict__ outp) {
  int dst = blockIdx.x * 4 + (threadIdx.x >> 6);
  if (dst >= N_NODES) return;
  int lane = threadIdx.x & 63;
  int rs = rowstart[dst], re = rs + degi[dst];
  float acc = 0.f;
  int j = rs;
  for (; j + 3 < re; j += 4) {
    int s0 = csr[j], s1 = csr[j + 1], s2 = csr[j + 2], s3 = csr[j + 3];
    float d0 = dinv[s0], d1 = dinv[s1], d2 = dinv[s2], d3 = dinv[s3];
    float v0 = bf2f(g[(size_t)s0 * 64 + lane]);
    float v1 = bf2f(g[(size_t)s1 * 64 + lane]);
    float v2 = bf2f(g[(size_t)s2 * 64 + lane]);
    float v3 = bf2f(g[(size_t)s3 * 64 + lane]);
    acc += (d0 * v0 + d1 * v1) + (d2 * v2 + d3 * v3);
  }
  for (; j < re; ++j) {
    int s0 = csr[j];
    acc += dinv[s0] * bf2f(g[(size_t)s0 * 64 + lane]);
  }
  float v = acc * dinv[dst] + bias[lane];
  outp[(size_t)dst * 64 + lane] = f2bf(fmaxf(v, 0.f));
}

// GCN layer-2 aggregation (bf16 g2) + bias, fused with drift-weighted combine
__global__ __launch_bounds__(256) void gcn_agg_fuse_bf(
    const int* __restrict__ rowstart, const int* __restrict__ degi, const int* __restrict__ csr,
    const ushort* __restrict__ g2, const float* __restrict__ dinv, const float* __restrict__ bg2,
    const float* __restrict__ hgat, const float* __restrict__ b2, const float* __restrict__ dw,
    float* __restrict__ outp) {
  int dst = blockIdx.x * 4 + (threadIdx.x >> 6);
  if (dst >= N_NODES) return;
  int lane = threadIdx.x & 63;
  int rs = rowstart[dst], re = rs + degi[dst];
  float acc = 0.f;
  int j = rs;
  for (; j + 3 < re; j += 4) {
    int s0 = csr[j], s1 = csr[j + 1], s2 = csr[j + 2], s3 = csr[j + 3];
    float d0 = dinv[s0], d1 = dinv[s1], d2 = dinv[s2], d3 = dinv[s3];
    float v0 = bf2f(g2[(size_t)s0 * 64 + lane]);
    float v1 = bf2f(g2[(size_t)s1 * 64 + lane]);
    float v2 = bf2f(g2[(size_t)s2 * 64 + lane]);
    float v3 = bf2f(g2[(size_t)s3 * 64 + lane]);
    acc += (d0 * v0 + d1 * v1) + (d2 * v2 + d3 * v3);
  }
  for (; j < re; ++j) {
    int s0 = csr[j];
    acc += dinv[s0] * bf2f(g2[(size_t)s0 * 64 + lane]);
  }
  float w = dw[0];
  float gcn = acc * dinv[dst] + bg2[lane];
  float gat = hgat[(size_t)dst * 64 + lane] + b2[lane];
  outp[(size_t)dst * 64 + lane] = w * gat + (1.f - w) * gcn;
}

// ---------------------------------------------------------------------------
// BatchNorm on bf16 activations (stats in fp32)
// ---------------------------------------------------------------------------
__global__ __launch_bounds__(256) void bn_stats_bf(
    const ushort* __restrict__ x, float* __restrict__ sum, float* __restrict__ sumsq) {
  int f = threadIdx.x;
  int r0 = blockIdx.x * 64;
  int rend = min(r0 + 64, N_NODES);
  float s = 0.f, s2 = 0.f;
  for (int r = r0; r < rend; ++r) {
    float v = bf2f(x[(size_t)r * 256 + f]);
    s += v; s2 += v * v;
  }
  atomicAdd(&sum[f], s);
  atomicAdd(&sumsq[f], s2);
}

// BN + ELU, in-place on bf16 (ushort4 vectorized)
__global__ __launch_bounds__(256) void bn_apply_bf(
    ushort* __restrict__ x, const float* __restrict__ sum, const float* __restrict__ sumsq,
    const float* __restrict__ gamma, const float* __restrict__ beta) {
  int i = blockIdx.x * 256 + threadIdx.x;           // chunk of 4
  if (i >= N_NODES * 64) return;
  int i4 = i * 4;
  int f0 = i4 & 255;
  const float invN = 1.0f / N_NODES;
  const float4 sm = *(const float4*)(sum + f0);
  const float4 sq = *(const float4*)(sumsq + f0);
  const float4 gm = *(const float4*)(gamma + f0);
  const float4 bt = *(const float4*)(beta + f0);
  ushort4 v = *(ushort4*)(x + i4);
  float mu, var, t;
  ushort4 o;
  mu = sm.x * invN; var = sq.x * invN - mu * mu;
  t = (bf2f(v.x) - mu) * rsqrtf(var + EPS) * gm.x + bt.x;
  o.x = f2bf(t > 0.f ? t : expf(t) - 1.0f);
  mu = sm.y * invN; var = sq.y * invN - mu * mu;
  t = (bf2f(v.y) - mu) * rsqrtf(var + EPS) * gm.y + bt.y;
  o.y = f2bf(t > 0.f ? t : expf(t) - 1.0f);
  mu = sm.z * invN; var = sq.z * invN - mu * mu;
  t = (bf2f(v.z) - mu) * rsqrtf(var + EPS) * gm.z + bt.z;
  o.z = f2bf(t > 0.f ? t : expf(t) - 1.0f);
  mu = sm.w * invN; var = sq.w * invN - mu * mu;
  t = (bf2f(v.w) - mu) * rsqrtf(var + EPS) * gm.w + bt.w;
  o.w = f2bf(t > 0.f ? t : expf(t) - 1.0f);
  *(ushort4*)(x + i4) = o;
}

extern "C" void kernel_launch(void* const* d_in, const int* in_sizes, int n_in,
                              void* d_out, int out_size, void* d_ws, size_t ws_size,
                              hipStream_t stream) {
  const float* x     = (const float*)d_in[0];
  const int*   ei    = (const int*)d_in[1];
  const float* dw    = (const float*)d_in[2];
  const float* W1    = (const float*)d_in[3];
  const float* as1   = (const float*)d_in[4];
  const float* ad1   = (const float*)d_in[5];
  // d_in[6] = b1: cancels through BatchNorm
  const float* gamma = (const float*)d_in[7];
  const float* beta  = (const float*)d_in[8];
  const float* W2    = (const float*)d_in[9];
  const float* as2   = (const float*)d_in[10];
  const float* ad2   = (const float*)d_in[11];
  const float* b2    = (const float*)d_in[12];
  const float* Wg1   = (const float*)d_in[13];
  const float* bg1   = (const float*)d_in[14];
  const float* Wg2   = (const float*)d_in[15];
  const float* bg2   = (const float*)d_in[16];
  float* out = (float*)d_out;

  char* p = (char*)d_ws;
  size_t off = 0;
  auto alloc = [&](size_t bytes) {
    char* r = p + off;
    off = (off + bytes + 255) & ~(size_t)255;
    return r;
  };
  ushort* aggbf = (ushort*)alloc((size_t)M_PAD * 256 * 2);    // agg1 out bf16 -> BN in-place -> h2 GEMM A
  ushort* h2p   = (ushort*)alloc((size_t)N_NODES * 256 * 2);  // permuted h2
  float*  bufC  = (float*)alloc((size_t)N_NODES * 64 * 4);    // h_gat fp32
  ushort* xbf   = (ushort*)alloc((size_t)M_PAD * 128 * 2);    // x bf16 (GEMM-A, padded)
  ushort* R1    = (ushort*)alloc((size_t)M_PAD * 256 * 2);    // h1 bf16 (GEMM-A, padded)
  ushort* g1bf  = (ushort*)alloc((size_t)N_NODES * 64 * 2);
  ushort* gbf   = (ushort*)alloc((size_t)M_PAD * 64 * 2);     // relu(g) bf16 (GEMM-A, padded)
  ushort* g2bf  = (ushort*)alloc((size_t)N_NODES * 64 * 2);
  ushort* w1t   = (ushort*)alloc((size_t)256 * 128 * 2);
  ushort* w2t   = (ushort*)alloc((size_t)256 * 256 * 2);
  ushort* wg1t  = (ushort*)alloc((size_t)64 * 128 * 2);
  ushort* wg2t  = (ushort*)alloc((size_t)64 * 64 * 2);
  float*  ssrc1 = (float*)alloc((size_t)N_NODES * 4 * 4);
  float*  sdst1 = (float*)alloc((size_t)N_NODES * 4 * 4);
  float*  ssrc2 = (float*)alloc((size_t)N_NODES * 4 * 4);
  float*  sdst2 = (float*)alloc((size_t)N_NODES * 4 * 4);
  char*   zr    = alloc((size_t)N_NODES * 4 + 512 * 4);       // degi + bnsum + bnsq (one memset)
  int*    degi  = (int*)zr;
  float*  bnsum = (float*)(zr + (size_t)N_NODES * 4);
  float*  bnsq  = bnsum + 256;
  int*    rowst = (int*)alloc((size_t)N_NODES * 4);
  int*    cursor= (int*)alloc((size_t)N_NODES * 4);
  int*    bsum  = (int*)alloc(SCAN_BLOCKS * 4);
  float*  dinv  = (float*)alloc((size_t)N_NODES * 4);
  int*    csr   = (int*)alloc((size_t)ETOT * 4);
  int*    csrd  = (int*)alloc((size_t)ETOT * 4);
  float*  pcsr  = (float*)alloc((size_t)ETOT * 4 * 4);        // per-edge probs [ETOT][4]

  const dim3 blk(256);
  const int egrid = (ETOT + 255) / 256;
  const int ngrid = 12500;

  hipMemsetAsync(zr, 0, (size_t)N_NODES * 4 + 512 * 4, stream);

  // ---- prep: pads + weight transposes (1 kernel) + x cast ----
  prep_small<<<459, blk, 0, stream>>>(W1, W2, Wg1, Wg2, w1t, w2t, wg1t, wg2t,
                                      R1 + (size_t)N_NODES * 256,
                                      aggbf + (size_t)N_NODES * 256,
                                      gbf + (size_t)N_NODES * 64);
  cast_x_bf16<<<(M_PAD * 32 + 255) / 256, blk, 0, stream>>>(x, xbf);

  // ---- CSR build ----
  deg_count_int<<<egrid, blk, 0, stream>>>(ei, degi);
  scan1<<<SCAN_BLOCKS, blk, 0, stream>>>(degi, rowst, bsum);
  scan2<<<1, blk, 0, stream>>>(bsum);
  scan3<<<SCAN_BLOCKS, blk, 0, stream>>>(rowst, bsum, cursor, degi, dinv);
  scatter_k<<<egrid, blk, 0, stream>>>(ei, cursor, csr, csrd);

  // ---- GEMMs off x (xbf dead after these) ----
  gemm_bf16<128, true, false><<<dim3(782, 4), blk, 0, stream>>>(xbf, w1t, R1, N_NODES, 256);    // h1
  gemm_bf16<128, true, false><<<dim3(782, 1), blk, 0, stream>>>(xbf, wg1t, g1bf, N_NODES, 64);  // g1

  // ---- GAT layer 1 ----
  attn_scores_bf<<<ngrid, blk, 0, stream>>>(R1, as1, ad1, ssrc1, sdst1);
  edge_p<<<egrid, blk, 0, stream>>>(csr, csrd, ssrc1, sdst1, pcsr);
  gat_agg1_bf<<<ngrid, blk, 0, stream>>>(rowst, degi, csr, pcsr, R1, aggbf);

  // ---- GCN layer 1 (independent) ----
  gcn_agg_relu_bf<<<ngrid, blk, 0, stream>>>(rowst, degi, csr, g1bf, dinv, bg1, gbf);
  gemm_bf16<64, true, false><<<dim3(782, 1), blk, 0, stream>>>(gbf, wg2t, g2bf, N_NODES, 64);   // g2

  // ---- BatchNorm + ELU (bf16 in/out, in-place on aggbf) ----
  bn_stats_bf<<<(N_NODES + 63) / 64, blk, 0, stream>>>(aggbf, bnsum, bnsq);
  bn_apply_bf<<<(N_NODES * 64 + 255) / 256, blk, 0, stream>>>(aggbf, bnsum, bnsq, gamma, beta);

  // ---- GAT layer 2: h2 written head-interleaved ----
  gemm_bf16<256, true, true><<<dim3(782, 4), blk, 0, stream>>>(aggbf, w2t, h2p, N_NODES, 256);  // h2 perm
  attn_scores_perm<<<ngrid, blk, 0, stream>>>(h2p, as2, ad2, ssrc2, sdst2);
  edge_p<<<egrid, blk, 0, stream>>>(csr, csrd, ssrc2, sdst2, pcsr);
  gat_agg2_perm<<<ngrid, blk, 0, stream>>>(rowst, degi, csr, pcsr, h2p, bufC);

  // ---- GCN layer 2 + drift-weighted fusion ----
  gcn_agg_fuse_bf<<<ngrid, blk, 0, stream>>>(rowst, degi, csr, g2bf, dinv, bg2, bufC, b2, dw, out);
}